// Round 17
// baseline (258.783 us; speedup 1.0000x reference)
//
#include <hip/hip_runtime.h>
#include <hip/hip_bf16.h>

// TemporalEncoderLayer: LN1 -> QKV -> windowed+global attention -> Wo+res -> LN2 -> GELU MLP + res
// B=2 S=2048 D=1024 H=16 DH=64 HALF_WIN=256. fp32 I/O, bf16 MFMA compute.
// R17 = R16 with ALL four GEMMs unified on the R16-validated BK=64 structure
// (64x128 tile, 16 MFMA/iter/wave, half the barriers of BK=32).

typedef __bf16 bf16x8 __attribute__((ext_vector_type(8)));
typedef float f32x4 __attribute__((ext_vector_type(4)));
typedef unsigned short u16;
typedef u16 u16x8 __attribute__((ext_vector_type(8)));
typedef u16 u16x4 __attribute__((ext_vector_type(4)));
typedef unsigned long long u64;

#define MBYTE (1ull << 20)

static __device__ __forceinline__ u16 f2bf(float f) {
  union { __hip_bfloat16 h; u16 u; } cv;
  cv.h = __float2bfloat16(f);
  return cv.u;
}

static __device__ __forceinline__ float bf2f(u16 u) {
  return __uint_as_float(((unsigned int)u) << 16);
}

static __device__ __forceinline__ float fexp2(float x) {
#if __has_builtin(__builtin_amdgcn_exp2f)
  return __builtin_amdgcn_exp2f(x);
#else
  return __expf(x * 0.6931471805599453f);
#endif
}

// tanh-form GELU via exp2 (~11 VALU ops vs ~25-30 for erff; max abs err ~1.5e-3)
static __device__ __forceinline__ float fast_gelu(float v) {
  float u = v * (0.7978845608028654f + 0.035677408136300125f * v * v);
  float e = fexp2(u * 2.885390081777927f);  // exp(2u)
  float th = 1.0f - 2.0f / (e + 1.0f);      // tanh(u)
  return 0.5f * v * (1.0f + th);
}

static __device__ __forceinline__ void gl_lds16(const void* g, void* l) {
  __builtin_amdgcn_global_load_lds((const __attribute__((address_space(1))) unsigned int*)g,
                                   (__attribute__((address_space(3))) unsigned int*)l, 16, 0, 0);
}

// XCD-aware block swizzle (grid % 8 == 0): contiguous tile chunk per XCD L2.
static __device__ __forceinline__ int xcd_swz(int bid, int nwg) {
  return (bid & 7) * (nwg >> 3) + (bid >> 3);
}

// ---------------- prep + weight transposes, one kernel ----------------
__global__ __launch_bounds__(256, 4) void transpose_all(
    const float* __restrict__ s0, const float* __restrict__ s1, const float* __restrict__ s2,
    const float* __restrict__ s3, const float* __restrict__ w1, const float* __restrict__ w2,
    u16* __restrict__ dqkvo, u16* __restrict__ d1, u16* __restrict__ d2,
    const unsigned char* __restrict__ g, u64* __restrict__ isgq,
    const float* __restrict__ bq, const float* __restrict__ bk,
    const float* __restrict__ bv, float* __restrict__ bias) {
  int bid = blockIdx.x;
  int t = threadIdx.x;
  if (bid >= 12288) {
    int local = bid - 12288;
    if (local < 12) {
      int i = local * 256 + t;
      float v = (i < 1024) ? bq[i] : (i < 2048) ? bk[i - 1024] : bv[i - 2048];
      bias[i] = v;
      return;
    }
    unsigned int acc = 0;
    for (int i = t; i < 4096; i += 256)
      if (i & 3) acc |= g[i];
    unsigned long long any = __ballot(acc != 0);
    __shared__ unsigned int r4[4];
    if ((t & 63) == 0) r4[t >> 6] = (any != 0) ? 1u : 0u;
    __syncthreads();
    int isInt = (r4[0] | r4[1] | r4[2] | r4[3]) ? 0 : 1;
    if (t < 64) {
      const int* g32 = (const int*)g;
      u64 w = 0;
      for (int j = 0; j < 64; ++j) {
        int idx = t * 64 + j;
        int v = isInt ? g32[idx] : (int)g[idx];
        w |= (u64)(v != 0 ? 1u : 0u) << j;
      }
      isgq[t] = w;
    }
    return;
  }
  __shared__ float tile[32][33];
  const float* src;
  u16* dst;
  int R, C, local;
  if (bid < 4096) {
    int sel = bid >> 10;
    src = (sel == 0) ? s0 : (sel == 1) ? s1 : (sel == 2) ? s2 : s3;
    dst = dqkvo + (size_t)sel * 1024 * 1024;
    R = 1024; C = 1024; local = bid & 1023;
  } else if (bid < 8192) {
    src = w1; dst = d1; R = 1024; C = 4096; local = bid - 4096;
  } else {
    src = w2; dst = d2; R = 4096; C = 1024; local = bid - 8192;
  }
  int nCx = C >> 5;
  int bx = local % nCx, by = local / nCx;
  int tx = t & 31, ty = t >> 5;
#pragma unroll
  for (int i = 0; i < 32; i += 8)
    tile[ty + i][tx] = src[(size_t)(by * 32 + ty + i) * C + bx * 32 + tx];
  __syncthreads();
#pragma unroll
  for (int i = 0; i < 32; i += 8)
    dst[(size_t)(bx * 32 + ty + i) * R + by * 32 + tx] = f2bf(tile[tx][ty + i]);
}

// LayerNorm [4096][1024] -> bf16 [4096][1024]; input fp32 (BFIN=false) or bf16 (BFIN=true)
template <bool BFIN>
__global__ __launch_bounds__(256, 4) void layernorm_k(const void* __restrict__ xin,
                                                      const float* __restrict__ gam,
                                                      const float* __restrict__ bet,
                                                      u16* __restrict__ out) {
  int row = blockIdx.x, t = threadIdx.x;
  float4 v;
  if (BFIN) {
    u16x4 raw = ((const u16x4*)((const u16*)xin + (size_t)row * 1024))[t];
    v.x = bf2f(raw[0]); v.y = bf2f(raw[1]); v.z = bf2f(raw[2]); v.w = bf2f(raw[3]);
  } else {
    v = ((const float4*)((const float*)xin + (size_t)row * 1024))[t];
  }
  float s = v.x + v.y + v.z + v.w;
  float ss = v.x * v.x + v.y * v.y + v.z * v.z + v.w * v.w;
#pragma unroll
  for (int d = 1; d < 64; d <<= 1) {
    s += __shfl_xor(s, d);
    ss += __shfl_xor(ss, d);
  }
  __shared__ float ps[8];
  int w = t >> 6, l = t & 63;
  if (l == 0) { ps[w] = s; ps[4 + w] = ss; }
  __syncthreads();
  s = ps[0] + ps[1] + ps[2] + ps[3];
  ss = ps[4] + ps[5] + ps[6] + ps[7];
  float mean = s * (1.0f / 1024.0f);
  float var = ss * (1.0f / 1024.0f) - mean * mean;
  float rstd = rsqrtf(var + 1e-5f);
  float4 gv = ((const float4*)gam)[t];
  float4 bv = ((const float4*)bet)[t];
  u16x4 o;
  o[0] = f2bf((v.x - mean) * rstd * gv.x + bv.x);
  o[1] = f2bf((v.y - mean) * rstd * gv.y + bv.y);
  o[2] = f2bf((v.z - mean) * rstd * gv.z + bv.z);
  o[3] = f2bf((v.w - mean) * rstd * gv.w + bv.w);
  *(u16x4*)(out + (size_t)row * 1024 + t * 4) = o;
}

// ---------------- unified GEMM (BK=64, R16-validated): C = A*Bt^T + bias (+gelu) (+res) ----------------
// 64x128 tile, BK=64, 4 waves 2x2 (wave = 32x64), K/64 iterations, 16 MFMA/iter/wave.
// Proven 2-phase skeleton (one __syncthreads per iter) + R6-verified 8-chunk XOR layout:
// LDS[row][p] holds logical chunk p ^ (row&7); staged via pre-swizzled global src,
// dest = burst*4096B + t*16B (wave-uniform + lane*16 rule). Reads undo XOR, 2-way free.
// LDS 48KB -> 3 blocks/CU. RESMODE: 0 none, 1 fp32, 2 bf16. OUTMODE: 0 fp32, 1 bf16.
// VSPLIT (QKV): V-range columns (tn*128>=2048, block-uniform) written transposed to vtb.
template <int OUTMODE, bool DOGELU, int RESMODE, bool VSPLIT>
__global__ __launch_bounds__(256, 3) void gemm64(const u16* __restrict__ A,
                                                 const u16* __restrict__ Bt,
                                                 const float* __restrict__ bias,
                                                 const void* __restrict__ res,
                                                 void* __restrict__ Cout,
                                                 u16* __restrict__ vtb, int M, int N, int K) {
  __shared__ u16 As[2][64 * 64];
  __shared__ u16 Bs[2][128 * 64];
  const int t = threadIdx.x;
  const int w = t >> 6, l = t & 63, g = l >> 4, c = l & 15;
  const int wr = w >> 1, wc = w & 1;
  const int nTn = N >> 7;
  const int bid = xcd_swz(blockIdx.x, gridDim.x);
  const int tm = bid / nTn, tn = bid % nTn;

  f32x4 acc[2][4];
#pragma unroll
  for (int m = 0; m < 2; ++m)
#pragma unroll
    for (int n = 0; n < 4; ++n) acc[m][n] = (f32x4){0.f, 0.f, 0.f, 0.f};

  const int srow = t >> 3, sph = t & 7;  // row 0..31 per burst, phys chunk
  const int sch = sph ^ (srow & 7);      // pre-swizzled global chunk
  const u16* Ag = A + (size_t)(tm * 64 + srow) * K + sch * 8;
  const u16* Bg = Bt + (size_t)(tn * 128 + srow) * K + sch * 8;

#define STG64(buf, k0)                                                                 \
  {                                                                                    \
    _Pragma("unroll") for (int i = 0; i < 2; ++i)                                      \
        gl_lds16(Ag + (size_t)(i * 32) * K + (k0), (u16*)As[buf] + i * 2048 + t * 8);  \
    _Pragma("unroll") for (int i = 0; i < 4; ++i)                                      \
        gl_lds16(Bg + (size_t)(i * 32) * K + (k0), (u16*)Bs[buf] + i * 2048 + t * 8);  \
  }

  const int nt = K >> 6;
  STG64(0, 0);
  __syncthreads();
  int cur = 0;

  for (int it = 0; it < nt; ++it) {
    if (it + 1 < nt) STG64(cur ^ 1, (it + 1) * 64);
    bf16x8 af[2][2], bfr[4][2];
#pragma unroll
    for (int m = 0; m < 2; ++m) {
      int ar = wr * 32 + m * 16 + c;
#pragma unroll
      for (int kk = 0; kk < 2; ++kk)
        af[m][kk] = *(const bf16x8*)(As[cur] + ar * 64 + ((kk * 4 + g) ^ (c & 7)) * 8);
    }
#pragma unroll
    for (int n = 0; n < 4; ++n) {
      int br = wc * 64 + n * 16 + c;
#pragma unroll
      for (int kk = 0; kk < 2; ++kk)
        bfr[n][kk] = *(const bf16x8*)(Bs[cur] + br * 64 + ((kk * 4 + g) ^ (c & 7)) * 8);
    }
#pragma unroll
    for (int kk = 0; kk < 2; ++kk)
#pragma unroll
      for (int m = 0; m < 2; ++m)
#pragma unroll
        for (int n = 0; n < 4; ++n)
          acc[m][n] =
              __builtin_amdgcn_mfma_f32_16x16x32_bf16(af[m][kk], bfr[n][kk], acc[m][n], 0, 0, 0);
    __syncthreads();
    cur ^= 1;
  }
#undef STG64

  const bool vside = VSPLIT && (tn * 128 >= 2048);  // block-uniform (V boundary tile-aligned)
#pragma unroll
  for (int m = 0; m < 2; ++m) {
    int grow0 = tm * 64 + wr * 32 + m * 16 + g * 4;
#pragma unroll
    for (int n = 0; n < 4; ++n) {
      int gcol = tn * 128 + wc * 64 + n * 16 + c;
      float bv = bias[gcol];
      if (VSPLIT && vside) {
        // V fragment -> vtb[(b*16+h)*64+dh][s..s+3] as one u16x4
        int vc = gcol - 2048;
        int hh = vc >> 6, dh = vc & 63;
        int b_ = grow0 >> 11, s0 = grow0 & 2047;
        u16x4 pv;
#pragma unroll
        for (int r = 0; r < 4; ++r) pv[r] = f2bf(acc[m][n][r] + bv);
        *(u16x4*)(vtb + (size_t)((b_ * 16 + hh) * 64 + dh) * 2048 + s0) = pv;
      } else {
#pragma unroll
        for (int r = 0; r < 4; ++r) {
          int grow = grow0 + r;
          float v = acc[m][n][r] + bv;
          if (DOGELU) v = fast_gelu(v);
          if (RESMODE == 1) v += ((const float*)res)[(size_t)grow * N + gcol];
          if (RESMODE == 2) v += bf2f(((const u16*)res)[(size_t)grow * N + gcol]);
          if (OUTMODE == 1)
            ((u16*)Cout)[(size_t)grow * N + gcol] = f2bf(v);
          else
            ((float*)Cout)[(size_t)grow * N + gcol] = v;
        }
      }
    }
  }
}

// ---------------- fused windowed+global attention (R15/R16 verbatim) ----------------
__global__ __launch_bounds__(512, 3) void attn_fwd(const u16* __restrict__ qkv,
                                                   const u16* __restrict__ vt,
                                                   const u64* __restrict__ isgq,
                                                   u16* __restrict__ ctx) {
  __shared__ u16 Ks[2][64 * 64];   // [s][dh], chunk-XOR swizzled by (s&7)
  __shared__ u16 Vs[2][64 * 64];   // [dh][s], chunk-XOR swizzled by (dh&7)
  __shared__ u16 Ps[8][16 * 64];   // per-wave P, [q][s], swizzled by (q&7)
  const int t = threadIdx.x, w = t >> 6, l = t & 63, g = l >> 4, c = l & 15;
  const int bid = xcd_swz(blockIdx.x, 512);
  const int qb = bid & 15, h = (bid >> 4) & 15, b = bid >> 8;
  const int q0 = qb * 128 + w * 16;
  const float C2 = 0.18033688011112042f;  // 0.125 * log2(e)

  bf16x8 aq[2];
#pragma unroll
  for (int kf = 0; kf < 2; ++kf) {
    bf16x8 raw = *(const bf16x8*)(qkv + (size_t)(b * 2048 + q0 + c) * 3072 +
                                  h * 64 + kf * 32 + g * 8);
#pragma unroll
    for (int j = 0; j < 8; ++j) aq[kf][j] = (__bf16)((float)raw[j] * C2);
  }

  const u64 qw = isgq[b * 32 + (q0 >> 6)];
  bool qflag[4];
#pragma unroll
  for (int r = 0; r < 4; ++r) qflag[r] = (qw >> ((q0 & 63) + g * 4 + r)) & 1;

  bf16x8 vone;
#pragma unroll
  for (int j = 0; j < 8; ++j) vone[j] = (__bf16)1.0f;

  int poff[4][4];
#pragma unroll
  for (int n = 0; n < 4; ++n)
#pragma unroll
    for (int r = 0; r < 4; ++r) {
      int qr = g * 4 + r, scol = n * 16 + c;
      poff[n][r] = qr * 128 + ((scol * 2) ^ ((qr & 7) << 4));
    }

  f32x4 o[4], ol;
#pragma unroll
  for (int n = 0; n < 4; ++n) o[n] = (f32x4){0.f, 0.f, 0.f, 0.f};
  ol = (f32x4){0.f, 0.f, 0.f, 0.f};

  const int stR = t >> 3, stC = t & 7;
  const int qa0 = q0 + g * 4;

#define STAGE(buf, kt)                                                                       \
  {                                                                                          \
    int ch_ = stC ^ (stR & 7);                                                               \
    gl_lds16(qkv + (size_t)(b * 2048 + (kt)*64 + stR) * 3072 + 1024 + h * 64 + ch_ * 8,      \
             (u16*)Ks[buf] + stR * 64 + stC * 8);                                            \
    gl_lds16(vt + (size_t)((b * 16 + h) * 64 + stR) * 2048 + (kt)*64 + ch_ * 8,              \
             (u16*)Vs[buf] + stR * 64 + stC * 8);                                            \
  }

  STAGE(0, 0);
  __syncthreads();
  int cur = 0;

  for (int kt = 0; kt < 32; ++kt) {
    if (kt + 1 < 32) STAGE(cur ^ 1, kt + 1);
    const u64 kw = isgq[b * 32 + kt];

    f32x4 sf[4];
#pragma unroll
    for (int n = 0; n < 4; ++n) sf[n] = (f32x4){0.f, 0.f, 0.f, 0.f};
#pragma unroll
    for (int n = 0; n < 4; ++n) {
      int srw = n * 16 + c;
#pragma unroll
      for (int kf = 0; kf < 2; ++kf) {
        bf16x8 kb = *(const bf16x8*)((const char*)Ks[cur] + srw * 128 +
                                     ((kf * 64 + g * 16) ^ ((srw & 7) << 4)));
        sf[n] = __builtin_amdgcn_mfma_f32_16x16x32_bf16(aq[kf], kb, sf[n], 0, 0, 0);
      }
    }

    const int k64 = kt * 64;
    if (k64 >= q0 - 241 && k64 <= q0 + 193) {
#pragma unroll
      for (int n = 0; n < 4; ++n)
#pragma unroll
        for (int r = 0; r < 4; ++r)
          *(u16*)((char*)Ps[w] + poff[n][r]) = f2bf(fexp2(sf[n][r]));
    } else {
#pragma unroll
      for (int n = 0; n < 4; ++n) {
        int kcol = k64 + n * 16 + c;
        bool kfl = (kw >> (n * 16 + c)) & 1;
#pragma unroll
        for (int r = 0; r < 4; ++r) {
          int d = qa0 + r - kcol;
          bool ok = ((unsigned)(d + 256) <= 512u) || qflag[r] || kfl;
          float p = fexp2(ok ? sf[n][r] : -1e30f);
          *(u16*)((char*)Ps[w] + poff[n][r]) = f2bf(p);
        }
      }
    }

#pragma unroll
    for (int kf = 0; kf < 2; ++kf) {
      bf16x8 pa = *(const bf16x8*)((const char*)Ps[w] + c * 128 +
                                   ((kf * 64 + g * 16) ^ ((c & 7) << 4)));
#pragma unroll
      for (int n = 0; n < 4; ++n) {
        int dh = n * 16 + c;
        bf16x8 vb = *(const bf16x8*)((const char*)Vs[cur] + dh * 128 +
                                     ((kf * 64 + g * 16) ^ ((dh & 7) << 4)));
        o[n] = __builtin_amdgcn_mfma_f32_16x16x32_bf16(pa, vb, o[n], 0, 0, 0);
      }
      ol = __builtin_amdgcn_mfma_f32_16x16x32_bf16(pa, vone, ol, 0, 0, 0);
    }
    __syncthreads();
    cur ^= 1;
  }
#undef STAGE

#pragma unroll
  for (int r = 0; r < 4; ++r) {
    float inv = 1.0f / ol[r];
    int qg = q0 + g * 4 + r;
#pragma unroll
    for (int n = 0; n < 4; ++n)
      ctx[(size_t)(b * 2048 + qg) * 1024 + h * 64 + n * 16 + c] = f2bf(o[n][r] * inv);
  }
}

// ---------------- launcher ----------------

extern "C" void kernel_launch(void* const* d_in, const int* in_sizes, int n_in,
                              void* d_out, int out_size, void* d_ws, size_t ws_size,
                              hipStream_t stream) {
  (void)in_sizes; (void)n_in; (void)out_size; (void)ws_size;
  const float* x = (const float*)d_in[0];
  const unsigned char* isg = (const unsigned char*)d_in[1];
  const float* Wq = (const float*)d_in[2];
  const float* bq = (const float*)d_in[3];
  const float* Wk = (const float*)d_in[4];
  const float* bk = (const float*)d_in[5];
  const float* Wv = (const float*)d_in[6];
  const float* bv = (const float*)d_in[7];
  const float* Wo = (const float*)d_in[8];
  const float* bo = (const float*)d_in[9];
  const float* ln1g = (const float*)d_in[10];
  const float* ln1b = (const float*)d_in[11];
  const float* ln2g = (const float*)d_in[12];
  const float* ln2b = (const float*)d_in[13];
  const float* W1 = (const float*)d_in[14];
  const float* b1 = (const float*)d_in[15];
  const float* W2 = (const float*)d_in[16];
  const float* b2 = (const float*)d_in[17];

  char* ws = (char*)d_ws;
  u16* wqkvt = (u16*)(ws);                    // [3072][1024] bf16, 6MB (wot follows contiguously)
  u16* wot   = (u16*)(ws + 6 * MBYTE);        // [1024][1024], 2MB
  u16* w1t   = (u16*)(ws + 8 * MBYTE);        // [4096][1024], 8MB
  u16* w2t   = (u16*)(ws + 16 * MBYTE);       // [1024][4096], 8MB
  float* bqkv = (float*)(ws + 24 * MBYTE);    // [3072]
  u64* isgq  = (u64*)(ws + 24 * MBYTE + 65536);  // 64 qwords
  u16* hbuf  = (u16*)(ws + 25 * MBYTE);       // [4096][1024] bf16 (h, then h2)
  u16* qkvb  = (u16*)(ws + 33 * MBYTE);       // [4096][3072] bf16, 24MB (V slice unused)
  u16* vtb   = (u16*)(ws + 57 * MBYTE);       // [B*H*64][2048] bf16, 8MB
  u16* ctx   = (u16*)(ws + 65 * MBYTE);       // [4096][1024] bf16, 8MB
  u16* x1b   = (u16*)(ws + 73 * MBYTE);       // [4096][1024] bf16 residual stream, 8MB
  u16* ff1   = (u16*)(ws + 33 * MBYTE);       // [4096][4096] bf16, 32MB (aliases qkv+vt, dead by then)

  transpose_all<<<12301, 256, 0, stream>>>(Wq, Wk, Wv, Wo, W1, W2, wqkvt, w1t, w2t,
                                           isg, isgq, bq, bk, bv, bqkv);

  layernorm_k<false><<<4096, 256, 0, stream>>>(x, ln1g, ln1b, hbuf);
  gemm64<1, false, 0, true><<<1536, 256, 0, stream>>>(hbuf, wqkvt, bqkv, nullptr,
                                                      qkvb, vtb, 4096, 3072, 1024);
  attn_fwd<<<512, 512, 0, stream>>>(qkvb, vtb, isgq, ctx);
  gemm64<1, false, 1, false><<<512, 256, 0, stream>>>(ctx, wot, bo, x, x1b, nullptr,
                                                      4096, 1024, 1024);
  layernorm_k<true><<<4096, 256, 0, stream>>>(x1b, ln2g, ln2b, hbuf);
  gemm64<1, true, 0, false><<<2048, 256, 0, stream>>>(hbuf, w1t, b1, nullptr, ff1,
                                                      nullptr, 4096, 4096, 1024);
  gemm64<0, false, 2, false><<<512, 256, 0, stream>>>(ff1, w2t, b2, x1b, (float*)d_out,
                                                      nullptr, 4096, 1024, 4096);
}

// Round 18
// 247.379 us; speedup vs baseline: 1.0461x; 1.0461x over previous
//
#include <hip/hip_runtime.h>
#include <hip/hip_bf16.h>

// TemporalEncoderLayer: LN1 -> QKV -> windowed+global attention -> Wo+res -> LN2 -> GELU MLP + res
// B=2 S=2048 D=1024 H=16 DH=64 HALF_WIN=256. fp32 I/O, bf16 MFMA compute.
// R18 = R16 composition + gemm64 for Wo (BK=64 at unchanged 64x128 tile, W2-validated).
// R17 lesson: BK=64 wins ONLY at constant tile shape — shrinking BM 128->64 doubled
// B-panel re-reads (FETCH 44->103MB on W1) and regressed. QKV/W1 stay BM=128/BK=32.

typedef __bf16 bf16x8 __attribute__((ext_vector_type(8)));
typedef float f32x4 __attribute__((ext_vector_type(4)));
typedef unsigned short u16;
typedef u16 u16x8 __attribute__((ext_vector_type(8)));
typedef u16 u16x4 __attribute__((ext_vector_type(4)));
typedef unsigned long long u64;

#define MBYTE (1ull << 20)

static __device__ __forceinline__ u16 f2bf(float f) {
  union { __hip_bfloat16 h; u16 u; } cv;
  cv.h = __float2bfloat16(f);
  return cv.u;
}

static __device__ __forceinline__ float bf2f(u16 u) {
  return __uint_as_float(((unsigned int)u) << 16);
}

static __device__ __forceinline__ float fexp2(float x) {
#if __has_builtin(__builtin_amdgcn_exp2f)
  return __builtin_amdgcn_exp2f(x);
#else
  return __expf(x * 0.6931471805599453f);
#endif
}

// tanh-form GELU via exp2 (~11 VALU ops vs ~25-30 for erff; max abs err ~1.5e-3)
static __device__ __forceinline__ float fast_gelu(float v) {
  float u = v * (0.7978845608028654f + 0.035677408136300125f * v * v);
  float e = fexp2(u * 2.885390081777927f);  // exp(2u)
  float th = 1.0f - 2.0f / (e + 1.0f);      // tanh(u)
  return 0.5f * v * (1.0f + th);
}

static __device__ __forceinline__ void gl_lds16(const void* g, void* l) {
  __builtin_amdgcn_global_load_lds((const __attribute__((address_space(1))) unsigned int*)g,
                                   (__attribute__((address_space(3))) unsigned int*)l, 16, 0, 0);
}

// XCD-aware block swizzle (grid % 8 == 0): contiguous tile chunk per XCD L2.
static __device__ __forceinline__ int xcd_swz(int bid, int nwg) {
  return (bid & 7) * (nwg >> 3) + (bid >> 3);
}

// ---------------- prep + weight transposes, one kernel ----------------
__global__ __launch_bounds__(256, 4) void transpose_all(
    const float* __restrict__ s0, const float* __restrict__ s1, const float* __restrict__ s2,
    const float* __restrict__ s3, const float* __restrict__ w1, const float* __restrict__ w2,
    u16* __restrict__ dqkvo, u16* __restrict__ d1, u16* __restrict__ d2,
    const unsigned char* __restrict__ g, u64* __restrict__ isgq,
    const float* __restrict__ bq, const float* __restrict__ bk,
    const float* __restrict__ bv, float* __restrict__ bias) {
  int bid = blockIdx.x;
  int t = threadIdx.x;
  if (bid >= 12288) {
    int local = bid - 12288;
    if (local < 12) {
      int i = local * 256 + t;
      float v = (i < 1024) ? bq[i] : (i < 2048) ? bk[i - 1024] : bv[i - 2048];
      bias[i] = v;
      return;
    }
    unsigned int acc = 0;
    for (int i = t; i < 4096; i += 256)
      if (i & 3) acc |= g[i];
    unsigned long long any = __ballot(acc != 0);
    __shared__ unsigned int r4[4];
    if ((t & 63) == 0) r4[t >> 6] = (any != 0) ? 1u : 0u;
    __syncthreads();
    int isInt = (r4[0] | r4[1] | r4[2] | r4[3]) ? 0 : 1;
    if (t < 64) {
      const int* g32 = (const int*)g;
      u64 w = 0;
      for (int j = 0; j < 64; ++j) {
        int idx = t * 64 + j;
        int v = isInt ? g32[idx] : (int)g[idx];
        w |= (u64)(v != 0 ? 1u : 0u) << j;
      }
      isgq[t] = w;
    }
    return;
  }
  __shared__ float tile[32][33];
  const float* src;
  u16* dst;
  int R, C, local;
  if (bid < 4096) {
    int sel = bid >> 10;
    src = (sel == 0) ? s0 : (sel == 1) ? s1 : (sel == 2) ? s2 : s3;
    dst = dqkvo + (size_t)sel * 1024 * 1024;
    R = 1024; C = 1024; local = bid & 1023;
  } else if (bid < 8192) {
    src = w1; dst = d1; R = 1024; C = 4096; local = bid - 4096;
  } else {
    src = w2; dst = d2; R = 4096; C = 1024; local = bid - 8192;
  }
  int nCx = C >> 5;
  int bx = local % nCx, by = local / nCx;
  int tx = t & 31, ty = t >> 5;
#pragma unroll
  for (int i = 0; i < 32; i += 8)
    tile[ty + i][tx] = src[(size_t)(by * 32 + ty + i) * C + bx * 32 + tx];
  __syncthreads();
#pragma unroll
  for (int i = 0; i < 32; i += 8)
    dst[(size_t)(bx * 32 + ty + i) * R + by * 32 + tx] = f2bf(tile[tx][ty + i]);
}

// LayerNorm [4096][1024] -> bf16 [4096][1024]; input fp32 (BFIN=false) or bf16 (BFIN=true)
template <bool BFIN>
__global__ __launch_bounds__(256, 4) void layernorm_k(const void* __restrict__ xin,
                                                      const float* __restrict__ gam,
                                                      const float* __restrict__ bet,
                                                      u16* __restrict__ out) {
  int row = blockIdx.x, t = threadIdx.x;
  float4 v;
  if (BFIN) {
    u16x4 raw = ((const u16x4*)((const u16*)xin + (size_t)row * 1024))[t];
    v.x = bf2f(raw[0]); v.y = bf2f(raw[1]); v.z = bf2f(raw[2]); v.w = bf2f(raw[3]);
  } else {
    v = ((const float4*)((const float*)xin + (size_t)row * 1024))[t];
  }
  float s = v.x + v.y + v.z + v.w;
  float ss = v.x * v.x + v.y * v.y + v.z * v.z + v.w * v.w;
#pragma unroll
  for (int d = 1; d < 64; d <<= 1) {
    s += __shfl_xor(s, d);
    ss += __shfl_xor(ss, d);
  }
  __shared__ float ps[8];
  int w = t >> 6, l = t & 63;
  if (l == 0) { ps[w] = s; ps[4 + w] = ss; }
  __syncthreads();
  s = ps[0] + ps[1] + ps[2] + ps[3];
  ss = ps[4] + ps[5] + ps[6] + ps[7];
  float mean = s * (1.0f / 1024.0f);
  float var = ss * (1.0f / 1024.0f) - mean * mean;
  float rstd = rsqrtf(var + 1e-5f);
  float4 gv = ((const float4*)gam)[t];
  float4 bv = ((const float4*)bet)[t];
  u16x4 o;
  o[0] = f2bf((v.x - mean) * rstd * gv.x + bv.x);
  o[1] = f2bf((v.y - mean) * rstd * gv.y + bv.y);
  o[2] = f2bf((v.z - mean) * rstd * gv.z + bv.z);
  o[3] = f2bf((v.w - mean) * rstd * gv.w + bv.w);
  *(u16x4*)(out + (size_t)row * 1024 + t * 4) = o;
}

// ---------------- GEMM (BK=32, BM=128 family — proven for K=1024 big-N): ----------------
// MT*32 x 128 tile, BK=32, 4 waves 2x2, 2-phase dbuf, one __syncthreads per iter;
// LDS chunk swizzle phys = logical ^ ((row>>1)&3) via pre-swizzled global source.
// RESMODE: 0 none, 1 fp32, 2 bf16. VSPLIT: QKV V-slice -> vtb transposed (R14).
template <int MT, int OUTMODE, bool DOGELU, int RESMODE, bool VSPLIT>
__global__ __launch_bounds__(256, (MT == 4) ? 3 : 4) void gemm_bt(
    const u16* __restrict__ A, const u16* __restrict__ Bt, const float* __restrict__ bias,
    const void* __restrict__ res, void* __restrict__ Cout, u16* __restrict__ vtb,
    int M, int N, int K) {
  constexpr int BM = MT * 32;
  constexpr int MR = MT;
  constexpr int SI = MT / 2;
  __shared__ u16 As[2][BM * 32];
  __shared__ u16 Bs[2][128 * 32];
  const int t = threadIdx.x;
  const int w = t >> 6, l = t & 63, g = l >> 4, c = l & 15;
  const int wr = w >> 1, wc = w & 1;
  const int nTn = N >> 7;
  const int bid = xcd_swz(blockIdx.x, gridDim.x);
  const int tm = bid / nTn, tn = bid % nTn;

  f32x4 acc[MR][4];
#pragma unroll
  for (int m = 0; m < MR; ++m)
#pragma unroll
    for (int n = 0; n < 4; ++n) acc[m][n] = (f32x4){0.f, 0.f, 0.f, 0.f};

  const int srow = t >> 2, schunk = t & 3;

#define GSTAGE(buf, k0)                                                                   \
  {                                                                                       \
    _Pragma("unroll") for (int i = 0; i < SI; ++i) {                                      \
      int r_ = srow + i * 64;                                                             \
      int ch_ = schunk ^ ((r_ >> 1) & 3);                                                 \
      gl_lds16(A + (size_t)(tm * BM + r_) * K + (k0) + ch_ * 8,                           \
               (u16*)As[buf] + r_ * 32 + schunk * 8);                                     \
    }                                                                                     \
    _Pragma("unroll") for (int i = 0; i < 2; ++i) {                                       \
      int r_ = srow + i * 64;                                                             \
      int ch_ = schunk ^ ((r_ >> 1) & 3);                                                 \
      gl_lds16(Bt + (size_t)(tn * 128 + r_) * K + (k0) + ch_ * 8,                         \
               (u16*)Bs[buf] + r_ * 32 + schunk * 8);                                     \
    }                                                                                     \
  }

  const int nt = K >> 5;
  GSTAGE(0, 0);
  __syncthreads();
  int cur = 0;

  for (int it = 0; it < nt; ++it) {
    if (it + 1 < nt) GSTAGE(cur ^ 1, (it + 1) * 32);
    bf16x8 af[MR], bfr[4];
#pragma unroll
    for (int m = 0; m < MR; ++m) {
      int ar = wr * (MT * 16) + m * 16 + c;
      af[m] = *(const bf16x8*)(As[cur] + ar * 32 + (g ^ ((ar >> 1) & 3)) * 8);
    }
#pragma unroll
    for (int n = 0; n < 4; ++n) {
      int br = wc * 64 + n * 16 + c;
      bfr[n] = *(const bf16x8*)(Bs[cur] + br * 32 + (g ^ ((br >> 1) & 3)) * 8);
    }
#pragma unroll
    for (int m = 0; m < MR; ++m)
#pragma unroll
      for (int n = 0; n < 4; ++n)
        acc[m][n] = __builtin_amdgcn_mfma_f32_16x16x32_bf16(af[m], bfr[n], acc[m][n], 0, 0, 0);
    __syncthreads();
    cur ^= 1;
  }
#undef GSTAGE

  const bool vside = VSPLIT && (tn * 128 >= 2048);  // block-uniform (V boundary tile-aligned)
#pragma unroll
  for (int m = 0; m < MR; ++m) {
    int grow0 = tm * BM + wr * (MT * 16) + m * 16 + g * 4;
#pragma unroll
    for (int n = 0; n < 4; ++n) {
      int gcol = tn * 128 + wc * 64 + n * 16 + c;
      float bv = bias[gcol];
      if (VSPLIT && vside) {
        int vc = gcol - 2048;
        int hh = vc >> 6, dh = vc & 63;
        int b_ = grow0 >> 11, s0 = grow0 & 2047;
        u16x4 pv;
#pragma unroll
        for (int r = 0; r < 4; ++r) pv[r] = f2bf(acc[m][n][r] + bv);
        *(u16x4*)(vtb + (size_t)((b_ * 16 + hh) * 64 + dh) * 2048 + s0) = pv;
      } else {
#pragma unroll
        for (int r = 0; r < 4; ++r) {
          int grow = grow0 + r;
          float v = acc[m][n][r] + bv;
          if (DOGELU) v = fast_gelu(v);
          if (RESMODE == 1) v += ((const float*)res)[(size_t)grow * N + gcol];
          if (RESMODE == 2) v += bf2f(((const u16*)res)[(size_t)grow * N + gcol]);
          if (OUTMODE == 1)
            ((u16*)Cout)[(size_t)grow * N + gcol] = f2bf(v);
          else
            ((float*)Cout)[(size_t)grow * N + gcol] = v;
        }
      }
    }
  }
}

// ---------------- gemm64 (BK=64, 64x128 tile — validated for Wo/W2 shapes) ----------------
// 4 waves 2x2 (wave = 32x64), K/64 iterations, 16 MFMA/iter/wave, LDS 48KB -> 3 blocks/CU.
// 8-chunk XOR layout: LDS[row][p] = logical chunk p ^ (row&7), pre-swizzled global src.
template <int OUTMODE, int RESMODE>
__global__ __launch_bounds__(256, 3) void gemm64(const u16* __restrict__ A,
                                                 const u16* __restrict__ Bt,
                                                 const float* __restrict__ bias,
                                                 const void* __restrict__ res,
                                                 void* __restrict__ Cout, int M, int N, int K) {
  __shared__ u16 As[2][64 * 64];
  __shared__ u16 Bs[2][128 * 64];
  const int t = threadIdx.x;
  const int w = t >> 6, l = t & 63, g = l >> 4, c = l & 15;
  const int wr = w >> 1, wc = w & 1;
  const int nTn = N >> 7;
  const int bid = xcd_swz(blockIdx.x, gridDim.x);
  const int tm = bid / nTn, tn = bid % nTn;

  f32x4 acc[2][4];
#pragma unroll
  for (int m = 0; m < 2; ++m)
#pragma unroll
    for (int n = 0; n < 4; ++n) acc[m][n] = (f32x4){0.f, 0.f, 0.f, 0.f};

  const int srow = t >> 3, sph = t & 7;
  const int sch = sph ^ (srow & 7);
  const u16* Ag = A + (size_t)(tm * 64 + srow) * K + sch * 8;
  const u16* Bg = Bt + (size_t)(tn * 128 + srow) * K + sch * 8;

#define STG64(buf, k0)                                                                 \
  {                                                                                    \
    _Pragma("unroll") for (int i = 0; i < 2; ++i)                                      \
        gl_lds16(Ag + (size_t)(i * 32) * K + (k0), (u16*)As[buf] + i * 2048 + t * 8);  \
    _Pragma("unroll") for (int i = 0; i < 4; ++i)                                      \
        gl_lds16(Bg + (size_t)(i * 32) * K + (k0), (u16*)Bs[buf] + i * 2048 + t * 8);  \
  }

  const int nt = K >> 6;
  STG64(0, 0);
  __syncthreads();
  int cur = 0;

  for (int it = 0; it < nt; ++it) {
    if (it + 1 < nt) STG64(cur ^ 1, (it + 1) * 64);
    bf16x8 af[2][2], bfr[4][2];
#pragma unroll
    for (int m = 0; m < 2; ++m) {
      int ar = wr * 32 + m * 16 + c;
#pragma unroll
      for (int kk = 0; kk < 2; ++kk)
        af[m][kk] = *(const bf16x8*)(As[cur] + ar * 64 + ((kk * 4 + g) ^ (c & 7)) * 8);
    }
#pragma unroll
    for (int n = 0; n < 4; ++n) {
      int br = wc * 64 + n * 16 + c;
#pragma unroll
      for (int kk = 0; kk < 2; ++kk)
        bfr[n][kk] = *(const bf16x8*)(Bs[cur] + br * 64 + ((kk * 4 + g) ^ (c & 7)) * 8);
    }
#pragma unroll
    for (int kk = 0; kk < 2; ++kk)
#pragma unroll
      for (int m = 0; m < 2; ++m)
#pragma unroll
        for (int n = 0; n < 4; ++n)
          acc[m][n] =
              __builtin_amdgcn_mfma_f32_16x16x32_bf16(af[m][kk], bfr[n][kk], acc[m][n], 0, 0, 0);
    __syncthreads();
    cur ^= 1;
  }
#undef STG64

#pragma unroll
  for (int m = 0; m < 2; ++m) {
    int grow0 = tm * 64 + wr * 32 + m * 16 + g * 4;
#pragma unroll
    for (int n = 0; n < 4; ++n) {
      int gcol = tn * 128 + wc * 64 + n * 16 + c;
      float bv = bias[gcol];
#pragma unroll
      for (int r = 0; r < 4; ++r) {
        int grow = grow0 + r;
        float v = acc[m][n][r] + bv;
        if (RESMODE == 1) v += ((const float*)res)[(size_t)grow * N + gcol];
        if (RESMODE == 2) v += bf2f(((const u16*)res)[(size_t)grow * N + gcol]);
        if (OUTMODE == 1)
          ((u16*)Cout)[(size_t)grow * N + gcol] = f2bf(v);
        else
          ((float*)Cout)[(size_t)grow * N + gcol] = v;
      }
    }
  }
}

// ---------------- fused windowed+global attention (R15/R16 verbatim) ----------------
__global__ __launch_bounds__(512, 3) void attn_fwd(const u16* __restrict__ qkv,
                                                   const u16* __restrict__ vt,
                                                   const u64* __restrict__ isgq,
                                                   u16* __restrict__ ctx) {
  __shared__ u16 Ks[2][64 * 64];   // [s][dh], chunk-XOR swizzled by (s&7)
  __shared__ u16 Vs[2][64 * 64];   // [dh][s], chunk-XOR swizzled by (dh&7)
  __shared__ u16 Ps[8][16 * 64];   // per-wave P, [q][s], swizzled by (q&7)
  const int t = threadIdx.x, w = t >> 6, l = t & 63, g = l >> 4, c = l & 15;
  const int bid = xcd_swz(blockIdx.x, 512);
  const int qb = bid & 15, h = (bid >> 4) & 15, b = bid >> 8;
  const int q0 = qb * 128 + w * 16;
  const float C2 = 0.18033688011112042f;  // 0.125 * log2(e)

  bf16x8 aq[2];
#pragma unroll
  for (int kf = 0; kf < 2; ++kf) {
    bf16x8 raw = *(const bf16x8*)(qkv + (size_t)(b * 2048 + q0 + c) * 3072 +
                                  h * 64 + kf * 32 + g * 8);
#pragma unroll
    for (int j = 0; j < 8; ++j) aq[kf][j] = (__bf16)((float)raw[j] * C2);
  }

  const u64 qw = isgq[b * 32 + (q0 >> 6)];
  bool qflag[4];
#pragma unroll
  for (int r = 0; r < 4; ++r) qflag[r] = (qw >> ((q0 & 63) + g * 4 + r)) & 1;

  bf16x8 vone;
#pragma unroll
  for (int j = 0; j < 8; ++j) vone[j] = (__bf16)1.0f;

  int poff[4][4];
#pragma unroll
  for (int n = 0; n < 4; ++n)
#pragma unroll
    for (int r = 0; r < 4; ++r) {
      int qr = g * 4 + r, scol = n * 16 + c;
      poff[n][r] = qr * 128 + ((scol * 2) ^ ((qr & 7) << 4));
    }

  f32x4 o[4], ol;
#pragma unroll
  for (int n = 0; n < 4; ++n) o[n] = (f32x4){0.f, 0.f, 0.f, 0.f};
  ol = (f32x4){0.f, 0.f, 0.f, 0.f};

  const int stR = t >> 3, stC = t & 7;
  const int qa0 = q0 + g * 4;

#define STAGE(buf, kt)                                                                       \
  {                                                                                          \
    int ch_ = stC ^ (stR & 7);                                                               \
    gl_lds16(qkv + (size_t)(b * 2048 + (kt)*64 + stR) * 3072 + 1024 + h * 64 + ch_ * 8,      \
             (u16*)Ks[buf] + stR * 64 + stC * 8);                                            \
    gl_lds16(vt + (size_t)((b * 16 + h) * 64 + stR) * 2048 + (kt)*64 + ch_ * 8,              \
             (u16*)Vs[buf] + stR * 64 + stC * 8);                                            \
  }

  STAGE(0, 0);
  __syncthreads();
  int cur = 0;

  for (int kt = 0; kt < 32; ++kt) {
    if (kt + 1 < 32) STAGE(cur ^ 1, kt + 1);
    const u64 kw = isgq[b * 32 + kt];

    f32x4 sf[4];
#pragma unroll
    for (int n = 0; n < 4; ++n) sf[n] = (f32x4){0.f, 0.f, 0.f, 0.f};
#pragma unroll
    for (int n = 0; n < 4; ++n) {
      int srw = n * 16 + c;
#pragma unroll
      for (int kf = 0; kf < 2; ++kf) {
        bf16x8 kb = *(const bf16x8*)((const char*)Ks[cur] + srw * 128 +
                                     ((kf * 64 + g * 16) ^ ((srw & 7) << 4)));
        sf[n] = __builtin_amdgcn_mfma_f32_16x16x32_bf16(aq[kf], kb, sf[n], 0, 0, 0);
      }
    }

    const int k64 = kt * 64;
    if (k64 >= q0 - 241 && k64 <= q0 + 193) {
#pragma unroll
      for (int n = 0; n < 4; ++n)
#pragma unroll
        for (int r = 0; r < 4; ++r)
          *(u16*)((char*)Ps[w] + poff[n][r]) = f2bf(fexp2(sf[n][r]));
    } else {
#pragma unroll
      for (int n = 0; n < 4; ++n) {
        int kcol = k64 + n * 16 + c;
        bool kfl = (kw >> (n * 16 + c)) & 1;
#pragma unroll
        for (int r = 0; r < 4; ++r) {
          int d = qa0 + r - kcol;
          bool ok = ((unsigned)(d + 256) <= 512u) || qflag[r] || kfl;
          float p = fexp2(ok ? sf[n][r] : -1e30f);
          *(u16*)((char*)Ps[w] + poff[n][r]) = f2bf(p);
        }
      }
    }

#pragma unroll
    for (int kf = 0; kf < 2; ++kf) {
      bf16x8 pa = *(const bf16x8*)((const char*)Ps[w] + c * 128 +
                                   ((kf * 64 + g * 16) ^ ((c & 7) << 4)));
#pragma unroll
      for (int n = 0; n < 4; ++n) {
        int dh = n * 16 + c;
        bf16x8 vb = *(const bf16x8*)((const char*)Vs[cur] + dh * 128 +
                                     ((kf * 64 + g * 16) ^ ((dh & 7) << 4)));
        o[n] = __builtin_amdgcn_mfma_f32_16x16x32_bf16(pa, vb, o[n], 0, 0, 0);
      }
      ol = __builtin_amdgcn_mfma_f32_16x16x32_bf16(pa, vone, ol, 0, 0, 0);
    }
    __syncthreads();
    cur ^= 1;
  }
#undef STAGE

#pragma unroll
  for (int r = 0; r < 4; ++r) {
    float inv = 1.0f / ol[r];
    int qg = q0 + g * 4 + r;
#pragma unroll
    for (int n = 0; n < 4; ++n)
      ctx[(size_t)(b * 2048 + qg) * 1024 + h * 64 + n * 16 + c] = f2bf(o[n][r] * inv);
  }
}

// ---------------- launcher ----------------

extern "C" void kernel_launch(void* const* d_in, const int* in_sizes, int n_in,
                              void* d_out, int out_size, void* d_ws, size_t ws_size,
                              hipStream_t stream) {
  (void)in_sizes; (void)n_in; (void)out_size; (void)ws_size;
  const float* x = (const float*)d_in[0];
  const unsigned char* isg = (const unsigned char*)d_in[1];
  const float* Wq = (const float*)d_in[2];
  const float* bq = (const float*)d_in[3];
  const float* Wk = (const float*)d_in[4];
  const float* bk = (const float*)d_in[5];
  const float* Wv = (const float*)d_in[6];
  const float* bv = (const float*)d_in[7];
  const float* Wo = (const float*)d_in[8];
  const float* bo = (const float*)d_in[9];
  const float* ln1g = (const float*)d_in[10];
  const float* ln1b = (const float*)d_in[11];
  const float* ln2g = (const float*)d_in[12];
  const float* ln2b = (const float*)d_in[13];
  const float* W1 = (const float*)d_in[14];
  const float* b1 = (const float*)d_in[15];
  const float* W2 = (const float*)d_in[16];
  const float* b2 = (const float*)d_in[17];

  char* ws = (char*)d_ws;
  u16* wqkvt = (u16*)(ws);                    // [3072][1024] bf16, 6MB (wot follows contiguously)
  u16* wot   = (u16*)(ws + 6 * MBYTE);        // [1024][1024], 2MB
  u16* w1t   = (u16*)(ws + 8 * MBYTE);        // [4096][1024], 8MB
  u16* w2t   = (u16*)(ws + 16 * MBYTE);       // [1024][4096], 8MB
  float* bqkv = (float*)(ws + 24 * MBYTE);    // [3072]
  u64* isgq  = (u64*)(ws + 24 * MBYTE + 65536);  // 64 qwords
  u16* hbuf  = (u16*)(ws + 25 * MBYTE);       // [4096][1024] bf16 (h, then h2)
  u16* qkvb  = (u16*)(ws + 33 * MBYTE);       // [4096][3072] bf16, 24MB (V slice unused)
  u16* vtb   = (u16*)(ws + 57 * MBYTE);       // [B*H*64][2048] bf16, 8MB
  u16* ctx   = (u16*)(ws + 65 * MBYTE);       // [4096][1024] bf16, 8MB
  u16* x1b   = (u16*)(ws + 73 * MBYTE);       // [4096][1024] bf16 residual stream, 8MB
  u16* ff1   = (u16*)(ws + 33 * MBYTE);       // [4096][4096] bf16, 32MB (aliases qkv+vt, dead by then)

  transpose_all<<<12301, 256, 0, stream>>>(Wq, Wk, Wv, Wo, W1, W2, wqkvt, w1t, w2t,
                                           isg, isgq, bq, bk, bv, bqkv);

  layernorm_k<false><<<4096, 256, 0, stream>>>(x, ln1g, ln1b, hbuf);
  gemm_bt<4, 1, false, 0, true><<<768, 256, 0, stream>>>(hbuf, wqkvt, bqkv, nullptr,
                                                         qkvb, vtb, 4096, 3072, 1024);
  attn_fwd<<<512, 512, 0, stream>>>(qkvb, vtb, isgq, ctx);
  gemm64<1, 1><<<512, 256, 0, stream>>>(ctx, wot, bo, x, x1b, 4096, 1024, 1024);
  layernorm_k<true><<<4096, 256, 0, stream>>>(x1b, ln2g, ln2b, hbuf);
  gemm_bt<4, 1, true, 0, false><<<1024, 256, 0, stream>>>(hbuf, w1t, b1, nullptr, ff1,
                                                          nullptr, 4096, 4096, 1024);
  gemm64<0, 2><<<512, 256, 0, stream>>>(ff1, w2t, b2, x1b, (float*)d_out, 4096, 1024, 4096);
}